// Round 1
// 224.809 us; speedup vs baseline: 1.2119x; 1.2119x over previous
//
#include <hip/hip_runtime.h>
#include <hip/hip_bf16.h>

#define B_  16
#define CI_ 32
#define H_  224
#define W_  224
#define CO_ 32
#define OH_ 222
#define OW_ 222
#define HW_ (H_*W_)      // 50176
#define K_  288          // CI_*9

// Fused-tile geometry: 8 oh rows x 64 ow x all 32 co per block (512 thr, 8 waves)
#define OHB   8
#define ROWS  10                 // OHB + 2 halo rows
#define OWT   64
#define PXT   66                 // OWT + 2 halo cols
#define NOHB  28                 // ceil(222/8)
#define NOWT  4                  // ceil(222/64)
#define NTASK (ROWS*PXT)         // 660 staging tasks per block
#define NBLK  (NOHB*NOWT*B_)     // 1792

typedef __attribute__((ext_vector_type(8))) short short8;   // 8 bf16 = 16B
typedef __attribute__((ext_vector_type(4))) float float4v;  // MFMA C/D
typedef float float4u __attribute__((ext_vector_type(4), aligned(4)));

// ---------------- weights: w[co][ci][kh][kw] fp32 -> wbf[co][g][ci] bf16 ----------------
__global__ void wprep(const float* __restrict__ w, unsigned short* __restrict__ wbf) {
    int idx = blockIdx.x * 256 + threadIdx.x;
    if (idx >= CO_ * K_) return;
    int co  = idx / K_;
    int rem = idx - co * K_;
    int ci  = rem / 9;
    int g   = rem - ci * 9;           // kh*3+kw
    unsigned int u = __float_as_uint(w[idx]);
    u = u + 0x7FFFu + ((u >> 16) & 1u);
    wbf[co * K_ + g * 32 + ci] = (unsigned short)(u >> 16);
}

// ---------------- fused conv: stage NCHW fp32 -> LDS NHWC bf16, then MFMA ----------------
// Stage: 660 tasks, each = one (row,px): gather 32 ci (two 16-deep load bursts, good MLP),
//        convert, 4x ds_write_b128 -> Xs[tr][p][ci] (66*32 shorts per row slab).
// Compute (identical verified MFMA structure to the two-pass kernel, A now from LDS):
//   A-frag: m=lane&15 (pixel), k=quad*8+j = ci  -> Xs[wv+kh][ot*16+i16+kw][quad*8..+7]
//   C/D: col(n=co)=lane&15, row(m=pixel)=quad*4+reg
// XCD swizzle: all 4 ow-tiles of one (b,ohblk) land on the SAME XCD (bid%8 assumed),
// temporally adjacent -> partial output sectors merge in that XCD's L2 (kills RMW).
__global__ __launch_bounds__(512, 4) void conv_fused(
    const float* __restrict__ x, const unsigned short* __restrict__ wbf,
    const float* __restrict__ bias, float* __restrict__ out)
{
    __shared__ unsigned short Xs[NTASK * CI_];   // 42,240 B -> 3 blocks/CU by LDS

    const int t   = threadIdx.x;
    const int bid = blockIdx.x;
    // bijective decode: xcd = bid&7, owt = (bid>>3)&3, gid = (bid>>5)*8 + xcd
    const int xcd   = bid & 7;
    const int owt   = (bid >> 3) & 3;
    const int gid   = (bid >> 5) * 8 + xcd;      // 0..447 = b*28 + ohblk
    const int b     = gid / NOHB;
    const int ohblk = gid - b * NOHB;
    const int r0    = ohblk * OHB;
    const int ow0   = owt * OWT;

    // ---- stage x[b][0:32][r0..r0+9][ow0..ow0+65] (edge-clamped) -> Xs ----
    for (int task = t; task < NTASK; task += 512) {
        const int tr = task / PXT;
        const int p  = task - tr * PXT;
        int row = r0 + tr;  if (row > H_ - 1) row = H_ - 1;   // clamped rows feed
        int col = ow0 + p;  if (col > W_ - 1) col = W_ - 1;   // discarded outputs only
        const float* xp = x + (size_t)b * CI_ * HW_ + (size_t)row * W_ + col;
        unsigned short* dst = &Xs[task * CI_];
#pragma unroll
        for (int h = 0; h < 2; ++h) {
            float f[16];
#pragma unroll
            for (int j = 0; j < 16; ++j) f[j] = xp[(size_t)(h * 16 + j) * HW_];
            union { short8 s8[2]; __hip_bfloat162 h2[8]; } u;
#pragma unroll
            for (int i = 0; i < 8; ++i)
                u.h2[i] = __float22bfloat162_rn(make_float2(f[2*i], f[2*i+1]));
            *(short8*)&dst[h * 16]     = u.s8[0];
            *(short8*)&dst[h * 16 + 8] = u.s8[1];
        }
    }
    __syncthreads();

    // ---- compute: wave wv handles oh = r0 + wv ----
    const int lane = t & 63;
    const int wv   = t >> 6;
    const int oh   = r0 + wv;
    if (oh >= OH_) return;            // after the only barrier -> safe early exit
    const int i16  = lane & 15;
    const int quad = lane >> 4;

    const unsigned short* wr0 = wbf + (size_t)i16 * K_;          // co = i16
    const unsigned short* wr1 = wbf + (size_t)(16 + i16) * K_;   // co = 16+i16

    float4v acc[4][2] = {};

#pragma unroll
    for (int g = 0; g < 9; ++g) {
        const int kh = g / 3;
        const int kw = g - kh * 3;
        const short8 b0 = *(const short8*)&wr0[g * 32 + quad * 8];
        const short8 b1 = *(const short8*)&wr1[g * 32 + quad * 8];
        const unsigned short* ar =
            &Xs[((wv + kh) * PXT + i16 + kw) * CI_ + quad * 8];
#pragma unroll
        for (int ot = 0; ot < 4; ++ot) {
            const short8 a = *(const short8*)&ar[ot * 16 * CI_];
            acc[ot][0] = __builtin_amdgcn_mfma_f32_16x16x32_bf16(a, b0, acc[ot][0], 0, 0, 0);
            acc[ot][1] = __builtin_amdgcn_mfma_f32_16x16x32_bf16(a, b1, acc[ot][1], 0, 0, 0);
        }
    }

    // ---- epilogue: per (ot,half) one dwordx4 -> 64B-contiguous runs per co-plane ----
    const float bv0 = bias[i16];
    const float bv1 = bias[16 + i16];
    const size_t o0 = ((size_t)(b * CO_ + i16) * OH_ + oh) * (size_t)OW_;
    const size_t o1 = ((size_t)(b * CO_ + 16 + i16) * OH_ + oh) * (size_t)OW_;
#pragma unroll
    for (int ot = 0; ot < 4; ++ot) {
        const int owq = ow0 + ot * 16 + quad * 4;
        float4u v0 = { acc[ot][0][0] + bv0, acc[ot][0][1] + bv0,
                       acc[ot][0][2] + bv0, acc[ot][0][3] + bv0 };
        float4u v1 = { acc[ot][1][0] + bv1, acc[ot][1][1] + bv1,
                       acc[ot][1][2] + bv1, acc[ot][1][3] + bv1 };
        if (owq + 3 < OW_) {
            *(float4u*)&out[o0 + owq] = v0;
            *(float4u*)&out[o1 + owq] = v1;
        } else {
#pragma unroll
            for (int r = 0; r < 4; ++r) {
                if (owq + r < OW_) {
                    out[o0 + owq + r] = acc[ot][0][r] + bv0;
                    out[o1 + owq + r] = acc[ot][1][r] + bv1;
                }
            }
        }
    }
}

extern "C" void kernel_launch(void* const* d_in, const int* in_sizes, int n_in,
                              void* d_out, int out_size, void* d_ws, size_t ws_size,
                              hipStream_t stream) {
    const float* x    = (const float*)d_in[0];
    const float* w    = (const float*)d_in[1];
    const float* bias = (const float*)d_in[2];
    float* out        = (float*)d_out;
    unsigned short* wbf = (unsigned short*)d_ws;                 // 18,432 B

    wprep<<<(CO_ * K_ + 255) / 256, 256, 0, stream>>>(w, wbf);
    conv_fused<<<dim3(NBLK), 512, 0, stream>>>(x, wbf, bias, out);
}

// Round 2
// 223.462 us; speedup vs baseline: 1.2192x; 1.0060x over previous
//
#include <hip/hip_runtime.h>
#include <hip/hip_bf16.h>

#define B_  16
#define CI_ 32
#define H_  224
#define W_  224
#define CO_ 32
#define OH_ 222
#define OW_ 222
#define HW_ (H_*W_)      // 50176
#define K_  288          // CI_*9

// Fused-tile geometry: 8 oh rows x 64 ow x all 32 co per block (512 thr, 8 waves)
#define OHB   8
#define ROWS  10                 // OHB + 2 halo rows
#define OWT   64
#define PXT   66                 // OWT + 2 halo cols
#define NOHB  28                 // ceil(222/8)
#define NOWT  4                  // ceil(222/64)
#define NPAIR (ROWS*(PXT/2))     // 330 float2 staging tasks (pixel pairs)
#define NBLK  (NOHB*NOWT*B_)     // 1792

typedef __attribute__((ext_vector_type(8))) short short8;   // 8 bf16 = 16B
typedef __attribute__((ext_vector_type(4))) float float4v;  // MFMA C/D
typedef float float4u __attribute__((ext_vector_type(4), aligned(4)));

// LDS swizzle: logical layout Xs[row][pixel][ci] (64 B per pixel). Pixel stride
// = 16 dwords == 0 mod 32 banks every 2 pixels -> reads were 4x, writes ~8x
// conflicted. Fix: XOR bits 4-6 (chunk + pixel parity) with bits 7-9 (pair idx).
// Involution, bijective within each 128 B pixel-pair region, keeps 16B alignment.
// Read check:  16 lanes/quad -> 2 lanes per 4-bank group = optimal 8 dw/bank.
// Write check: 64 lanes/chunk-instr -> 8 lanes per group = optimal 8 dw/bank.
__device__ __forceinline__ unsigned swz(unsigned L) {
    return L ^ (((L >> 7) & 7u) << 4);
}

// ---------------- weights: w[co][ci][kh][kw] fp32 -> wbf[co][g][ci] bf16 ----------------
__global__ void wprep(const float* __restrict__ w, unsigned short* __restrict__ wbf) {
    int idx = blockIdx.x * 256 + threadIdx.x;
    if (idx >= CO_ * K_) return;
    int co  = idx / K_;
    int rem = idx - co * K_;
    int ci  = rem / 9;
    int g   = rem - ci * 9;           // kh*3+kw
    unsigned int u = __float_as_uint(w[idx]);
    u = u + 0x7FFFu + ((u >> 16) & 1u);
    wbf[co * K_ + g * 32 + ci] = (unsigned short)(u >> 16);
}

// ---------------- fused conv: stage NCHW fp32 -> LDS NHWC bf16 (swizzled), MFMA ----------------
__global__ __launch_bounds__(512, 6) void conv_fused(
    const float* __restrict__ x, const unsigned short* __restrict__ wbf,
    const float* __restrict__ bias, float* __restrict__ out)
{
    __shared__ unsigned short Xs[ROWS * PXT * CI_];   // 42,240 B -> 3 blocks/CU

    const int t   = threadIdx.x;
    const int bid = blockIdx.x;
    // XCD swizzle: all 4 ow-tiles of one (b,ohblk) on the SAME XCD, temporally
    // adjacent -> partial output sectors merge in that XCD's L2 (verified R1:
    // WRITE 127->108 MB). bijective: bid = 32u + 8*owt + xcd -> gid = 8u + xcd.
    const int xcd   = bid & 7;
    const int owt   = (bid >> 3) & 3;
    const int gid   = (bid >> 5) * 8 + xcd;      // 0..447 = b*28 + ohblk
    const int b     = gid / NOHB;
    const int ohblk = gid - b * NOHB;
    const int r0    = ohblk * OHB;
    const int ow0   = owt * OWT;

    // ---- stage x[b][0:32][r0..r0+9][ow0..ow0+65] (edge-clamped) -> Xs ----
    // One float2 pixel-pair per thread: 32 8B loads (2 bursts of 16), whole
    // 128 B LDS region owned by this thread -> pair-level swizzle is safe.
    if (t < NPAIR) {
        const int tr = t / (PXT / 2);            // 0..9
        const int j  = t - tr * (PXT / 2);       // 0..32
        int row = r0 + tr;  if (row > H_ - 1) row = H_ - 1;   // clamped rows: unread
        const int c = ow0 + 2 * j;               // even; c+1<W_ <=> in-range pair
        const float* xp = x + (size_t)b * CI_ * HW_ + (size_t)row * W_;
        const unsigned base = (unsigned)(tr * PXT + 2 * j) * 64u;
#pragma unroll
        for (int h = 0; h < 2; ++h) {
            float2 f2[16];
            if (c + 1 < W_) {
#pragma unroll
                for (int i = 0; i < 16; ++i)
                    f2[i] = *(const float2*)&xp[(size_t)(h * 16 + i) * HW_ + c];
            } else {                              // c >= 224: both cols clamp to 223
#pragma unroll
                for (int i = 0; i < 16; ++i) {
                    float s = xp[(size_t)(h * 16 + i) * HW_ + (W_ - 1)];
                    f2[i] = make_float2(s, s);
                }
            }
            union { short8 s8[4]; __hip_bfloat162 h2[16]; } u;
#pragma unroll
            for (int i = 0; i < 8; ++i) {
                u.h2[i]     = __float22bfloat162_rn(make_float2(f2[2*i].x, f2[2*i+1].x)); // even px
                u.h2[8 + i] = __float22bfloat162_rn(make_float2(f2[2*i].y, f2[2*i+1].y)); // odd px
            }
            // chunk ids within the 128 B pair region: even px -> 2h,2h+1; odd -> 4+2h,5+2h
#pragma unroll
            for (int q2 = 0; q2 < 4; ++q2) {
                const int cc = (q2 < 2) ? (2 * h + q2) : (4 + 2 * h + (q2 - 2));
                *(short8*)((char*)Xs + swz(base + (unsigned)cc * 16u)) = u.s8[q2];
            }
        }
    }
    __syncthreads();

    // ---- compute: wave wv handles oh = r0 + wv ----
    const int lane = t & 63;
    const int wv   = t >> 6;
    const int oh   = r0 + wv;
    if (oh >= OH_) return;            // after the only barrier -> safe early exit
    const int i16  = lane & 15;
    const int quad = lane >> 4;

    const unsigned short* wr0 = wbf + (size_t)i16 * K_;          // co = i16
    const unsigned short* wr1 = wbf + (size_t)(16 + i16) * K_;   // co = 16+i16

    float4v acc[4][2] = {};

#pragma unroll
    for (int g = 0; g < 9; ++g) {
        const int kh = g / 3;
        const int kw = g - kh * 3;
        const short8 b0 = *(const short8*)&wr0[g * 32 + quad * 8];
        const short8 b1 = *(const short8*)&wr1[g * 32 + quad * 8];
        const unsigned rowbase = (unsigned)((wv + kh) * PXT) * 64u + (unsigned)quad * 16u;
#pragma unroll
        for (int ot = 0; ot < 4; ++ot) {
            const unsigned L = rowbase + (unsigned)(ot * 16 + i16 + kw) * 64u;
            const short8 a = *(const short8*)((const char*)Xs + swz(L));
            acc[ot][0] = __builtin_amdgcn_mfma_f32_16x16x32_bf16(a, b0, acc[ot][0], 0, 0, 0);
            acc[ot][1] = __builtin_amdgcn_mfma_f32_16x16x32_bf16(a, b1, acc[ot][1], 0, 0, 0);
        }
    }

    // ---- epilogue: per (ot,half) one dwordx4 -> 64B-contiguous runs per co-plane ----
    const float bv0 = bias[i16];
    const float bv1 = bias[16 + i16];
    const size_t o0 = ((size_t)(b * CO_ + i16) * OH_ + oh) * (size_t)OW_;
    const size_t o1 = ((size_t)(b * CO_ + 16 + i16) * OH_ + oh) * (size_t)OW_;
#pragma unroll
    for (int ot = 0; ot < 4; ++ot) {
        const int owq = ow0 + ot * 16 + quad * 4;
        float4u v0 = { acc[ot][0][0] + bv0, acc[ot][0][1] + bv0,
                       acc[ot][0][2] + bv0, acc[ot][0][3] + bv0 };
        float4u v1 = { acc[ot][1][0] + bv1, acc[ot][1][1] + bv1,
                       acc[ot][1][2] + bv1, acc[ot][1][3] + bv1 };
        if (owq + 3 < OW_) {
            *(float4u*)&out[o0 + owq] = v0;
            *(float4u*)&out[o1 + owq] = v1;
        } else {
#pragma unroll
            for (int r = 0; r < 4; ++r) {
                if (owq + r < OW_) {
                    out[o0 + owq + r] = acc[ot][0][r] + bv0;
                    out[o1 + owq + r] = acc[ot][1][r] + bv1;
                }
            }
        }
    }
}

extern "C" void kernel_launch(void* const* d_in, const int* in_sizes, int n_in,
                              void* d_out, int out_size, void* d_ws, size_t ws_size,
                              hipStream_t stream) {
    const float* x    = (const float*)d_in[0];
    const float* w    = (const float*)d_in[1];
    const float* bias = (const float*)d_in[2];
    float* out        = (float*)d_out;
    unsigned short* wbf = (unsigned short*)d_ws;                 // 18,432 B

    wprep<<<(CO_ * K_ + 255) / 256, 256, 0, stream>>>(w, wbf);
    conv_fused<<<dim3(NBLK), 512, 0, stream>>>(x, wbf, bias, out);
}